// Round 9
// baseline (216.768 us; speedup 1.0000x reference)
//
#include <hip/hip_runtime.h>
#include <stdint.h>

// Problem sizes (fixed): B=4, S=2048, D=1024, DQK=128, DV=256
#define SLEN 2048
#define NROWS 8192   // B*S

typedef __attribute__((ext_vector_type(4))) float f32x4;
typedef __attribute__((ext_vector_type(8))) short bf16x8;
typedef __attribute__((ext_vector_type(2))) unsigned int u32x2;
typedef __attribute__((ext_vector_type(4))) unsigned int u32x4;

__device__ __forceinline__ short f2bf(float f) {
  uint32_t u = __builtin_bit_cast(uint32_t, f);
  u += 0x7FFFu + ((u >> 16) & 1u);
  return (short)(u >> 16);
}
__device__ __forceinline__ float bf2f(short s) {
  uint32_t u = ((uint32_t)(uint16_t)s) << 16;
  return __builtin_bit_cast(float, u);
}
__device__ __forceinline__ f32x4 mfma16(bf16x8 a, bf16x8 b, f32x4 c) {
  return __builtin_amdgcn_mfma_f32_16x16x32_bf16(a, b, c, 0, 0, 0);
}
__device__ __forceinline__ void gld_lds16(const void* g, void* l) {
  __builtin_amdgcn_global_load_lds(
      (const __attribute__((address_space(1))) void*)g,
      (__attribute__((address_space(3))) void*)l, 16, 0, 0);
}

// ---------------------------------------------------------------- prep ------
// blocks [0,256): LDS-tiled 64x64 weight transposes; block 256: bcat.
// (X is no longer pre-cast: gemm1 reads it directly.)
__global__ __launch_bounds__(256) void k_prep(
    const float* __restrict__ Wq, const float* __restrict__ bq,
    const float* __restrict__ Wk, const float* __restrict__ bk,
    const float* __restrict__ Wv, const float* __restrict__ bv,
    const float* __restrict__ Wg, const float* __restrict__ bg,
    const float* __restrict__ Wp,
    short* __restrict__ WcatT, short* __restrict__ WpT,
    float* __restrict__ bcat) {
  __shared__ short tl[64][72];
  int blk = blockIdx.x, tid = threadIdx.x;
  if (blk < 256) {
    int t = blk;
    const float* src; short* dst; int C, rowoff, dstC, r0, c0;
    if (t < 32)       { src = Wq; C = 128;  rowoff = 0;   dst = WcatT; dstC = 1024; r0 = (t >> 1) * 64;  c0 = (t & 1) * 64; }
    else if (t < 64)  { t -= 32;  src = Wk; C = 128;  rowoff = 128; dst = WcatT; dstC = 1024; r0 = (t >> 1) * 64;  c0 = (t & 1) * 64; }
    else if (t < 128) { t -= 64;  src = Wv; C = 256;  rowoff = 256; dst = WcatT; dstC = 1024; r0 = (t >> 2) * 64;  c0 = (t & 3) * 64; }
    else if (t < 192) { t -= 128; src = Wg; C = 256;  rowoff = 512; dst = WcatT; dstC = 1024; r0 = (t >> 2) * 64;  c0 = (t & 3) * 64; }
    else              { t -= 192; src = Wp; C = 1024; rowoff = 0;   dst = WpT;   dstC = 256;  r0 = (t >> 4) * 64;  c0 = (t & 15) * 64; }
    int lr = tid >> 4, lcc = tid & 15;
#pragma unroll
    for (int rr = 0; rr < 4; ++rr) {
      f32x4 v = *(const f32x4*)&src[(size_t)(r0 + lr * 4 + rr) * C + c0 + lcc * 4];
#pragma unroll
      for (int j = 0; j < 4; ++j) tl[lcc * 4 + j][lr * 4 + rr] = f2bf(v[j]);
    }
    __syncthreads();
    int orow = tid >> 2, og = (tid & 3) * 16;
    bf16x8 o1, o2;
#pragma unroll
    for (int j = 0; j < 8; ++j) { o1[j] = tl[orow][og + j]; o2[j] = tl[orow][og + 8 + j]; }
    size_t dbase = (size_t)(rowoff + c0 + orow) * dstC + r0 + og;
    *(bf16x8*)&dst[dbase] = o1;
    *(bf16x8*)&dst[dbase + 8] = o2;
  } else {
    int c = tid;
    if (c < 768) {
      float v;
      if (c < 128)      v = bq[c];
      else if (c < 256) v = bk[c - 128];
      else if (c < 512) v = bv[c - 256];
      else              v = bg[c - 512];
      bcat[c] = v;
    }
  }
}

// ---------------------------------------------------------------- gemm1 -----
// O[8192][768] = bf16(X)[8192][1024] @ Wcat + bcat. A staged as f32 directly
// from X (chunk-XOR pre-swizzled source, linear LDS dest), converted to bf16
// at frag-load time -- numerically identical to the old Xb path.
// Blocks y==0/1 also emit q2a/k2a row norms.
__global__ __launch_bounds__(256) void k_gemm1(
    const float* __restrict__ X, const short* __restrict__ WcatT,
    const float* __restrict__ bcat, short* __restrict__ O,
    float* __restrict__ q2a, float* __restrict__ k2a) {
  __shared__ float Atf[128 * 32];   // 16 KB, 16B-chunk swizzled per row
  __shared__ short Bt[128 * 32];    //  8 KB
  __shared__ float nlds[128][2];
  const int tid = threadIdx.x;
  const int w = tid >> 6, l = tid & 63, lg = l >> 4, lc = l & 15;
  const int m0 = blockIdx.x * 128, n0 = blockIdx.y * 128;
  const int sr0 = w * 32 + (l >> 2);
  const int scc = (l & 3) * 8;
  const int wm = (w >> 1) * 64, wn = (w & 1) * 64;
  const int arow = w * 8 + (l >> 3);      // A-staging row within 32-row issue
  const int achk = (l & 7) ^ (arow & 7);  // pre-swizzled source chunk

  f32x4 acc[4][4] = {};
  const float* Ab = X + (size_t)m0 * 1024;
  const short* Bb = WcatT + (size_t)n0 * 1024;

  for (int kb = 0; kb < 1024; kb += 32) {
#pragma unroll
    for (int i = 0; i < 4; ++i)
      gld_lds16(Ab + (size_t)(i * 32 + arow) * 1024 + kb + achk * 4,
                &Atf[(i * 32 + w * 8) * 32 + l * 4]);
    gld_lds16(Bb + (size_t)sr0 * 1024 + kb + scc, &Bt[(w * 32) * 32]);
    gld_lds16(Bb + (size_t)(sr0 + 16) * 1024 + kb + scc, &Bt[(w * 32 + 16) * 32]);
    __syncthreads();
    bf16x8 af[4], bf[4];
#pragma unroll
    for (int mi = 0; mi < 4; ++mi) {
      int r = wm + mi * 16 + lc;
      f32x4 a0 = *(const f32x4*)&Atf[r * 32 + (((2 * lg) ^ (r & 7)) * 4)];
      f32x4 a1 = *(const f32x4*)&Atf[r * 32 + (((2 * lg + 1) ^ (r & 7)) * 4)];
#pragma unroll
      for (int j = 0; j < 4; ++j) {
        af[mi][j] = f2bf(a0[j]);
        af[mi][4 + j] = f2bf(a1[j]);
      }
    }
#pragma unroll
    for (int ni = 0; ni < 4; ++ni)
      bf[ni] = *(const bf16x8*)&Bt[(wn + ni * 16 + lc) * 32 + lg * 8];
#pragma unroll
    for (int mi = 0; mi < 4; ++mi)
#pragma unroll
      for (int ni = 0; ni < 4; ++ni)
        acc[mi][ni] = mfma16(af[mi], bf[ni], acc[mi][ni]);
    __syncthreads();
  }
  float sq[4][4] = {};
#pragma unroll
  for (int mi = 0; mi < 4; ++mi) {
    int gr = m0 + wm + mi * 16 + lg * 4;
#pragma unroll
    for (int ni = 0; ni < 4; ++ni) {
      int gc = n0 + wn + ni * 16 + lc;
      float bias = bcat[gc];
#pragma unroll
      for (int r = 0; r < 4; ++r) {
        short sv = f2bf(acc[mi][ni][r] + bias);
        O[(size_t)(gr + r) * 768 + gc] = sv;
        float v = bf2f(sv);
        sq[mi][r] += v * v;
      }
    }
  }
  if (blockIdx.y < 2) {
#pragma unroll
    for (int mi = 0; mi < 4; ++mi)
#pragma unroll
      for (int r = 0; r < 4; ++r) {
        float v = sq[mi][r];
        v += __shfl_xor(v, 1, 64); v += __shfl_xor(v, 2, 64);
        v += __shfl_xor(v, 4, 64); v += __shfl_xor(v, 8, 64);
        sq[mi][r] = v;
      }
    if (lc == 0) {
#pragma unroll
      for (int mi = 0; mi < 4; ++mi)
#pragma unroll
        for (int r = 0; r < 4; ++r)
          nlds[wm + mi * 16 + lg * 4 + r][w & 1] = sq[mi][r];
    }
    __syncthreads();
    if (tid < 128) {
      float t = nlds[tid][0] + nlds[tid][1];
      (blockIdx.y == 0 ? q2a : k2a)[m0 + tid] = t;
    }
  }
}

// ---------------------------------------------------------------- vt --------
// Vtp: V transposed AND k-permuted to match the in-register P fragment:
// pos(k) = (k>>5)*32 + ((k>>2)&3)*8 + ((k>>4)&1)*4 + (k&3)
__global__ __launch_bounds__(256) void k_vt(
    const short* __restrict__ O, short* __restrict__ Vtp) {
  __shared__ short tile[64][33];
  int blk = blockIdx.x, tid = threadIdx.x;
  int b = blk >> 8, rem = blk & 255;
  int s0 = (rem >> 3) * 64, dv0 = (rem & 7) * 32;
  int r = tid >> 2, cg = (tid & 3) * 8;
  bf16x8 v = *(const bf16x8*)&O[(size_t)(b * SLEN + s0 + r) * 768 + 256 + dv0 + cg];
#pragma unroll
  for (int j = 0; j < 8; ++j) tile[r][cg + j] = v[j];
  __syncthreads();
  int dr = tid >> 3, sg = (tid & 7) * 8;
  bf16x8 ov;
#pragma unroll
  for (int j = 0; j < 8; ++j) ov[j] = tile[sg + j][dr];
  int ka = s0 + sg;
  int c5 = ka >> 5, hi = (ka >> 4) & 1, lgq = (ka >> 2) & 3;
  size_t base = (size_t)(b * 256 + dv0 + dr) * SLEN + c5 * 32 + lgq * 8 + hi * 4;
  u32x4 od = __builtin_bit_cast(u32x4, ov);
  u32x2 p0; p0[0] = od[0]; p0[1] = od[1];
  u32x2 p1; p1[0] = od[2]; p1[1] = od[3];
  *(u32x2*)&Vtp[base] = p0;        // k = ka..ka+3
  *(u32x2*)&Vtp[base + 8] = p1;    // k = ka+4..ka+7
}

// ---------------------------------------------------------------- attn ------
// (unchanged from round 8 -- the proven 8-wave flash structure)
__global__ __launch_bounds__(512) void k_attn(
    const short* __restrict__ O, const short* __restrict__ Vtp,
    const float* __restrict__ q2a, const float* __restrict__ k2a,
    short* __restrict__ nump, float* __restrict__ denp) {
  __shared__ short Klds[2][64 * 128];
  __shared__ short Vlds[2][256 * 64];
  const int tid = threadIdx.x;
  const int w = tid >> 6, l = tid & 63, lg = l >> 4, lc = l & 15;
  const int gid = blockIdx.x;
  const int blk = ((gid & 7) << 5) | (gid >> 3);
  const int b = blk >> 6, qt = (blk >> 2) & 15, ks = blk & 3;
  const int grow0 = b * SLEN + qt * 128 + w * 16;
  const int kbase = ks * 512;

  bf16x8 qf[4];
#pragma unroll
  for (int kf = 0; kf < 4; ++kf)
    qf[kf] = *(const bf16x8*)&O[(size_t)(grow0 + lc) * 768 + kf * 32 + lg * 8];
  const float q2s = q2a[grow0 + lc];

  f32x4 acc[16] = {};
  float den = 0.f;

#define STAGE(T, BSEL)                                                        \
  {                                                                           \
    const int kt_ = kbase + (T) * 64;                                         \
    _Pragma("unroll")                                                         \
    for (int j = 0; j < 6; ++j) {                                             \
      int issue = w * 6 + j;                                                  \
      if (issue < 16) {                                                       \
        int kk = issue * 4 + (l >> 4);                                        \
        int c = l & 15;                                                       \
        const short* src = O + (size_t)(b * SLEN + kt_ + kk) * 768 + 128 +    \
                           ((c ^ (kk & 7)) * 8);                              \
        gld_lds16(src, &Klds[BSEL][issue * 512 + l * 8]);                     \
      } else {                                                                \
        int vj = issue - 16;                                                  \
        int dv = vj * 8 + (l >> 3);                                           \
        int c = l & 7;                                                        \
        const short* src = Vtp + (size_t)(b * 256 + dv) * SLEN + kt_ +        \
                           ((c ^ (dv & 7)) * 8);                              \
        gld_lds16(src, &Vlds[BSEL][vj * 512 + l * 8]);                        \
      }                                                                       \
    }                                                                         \
  }

  STAGE(0, 0);
  for (int t = 0; t < 8; ++t) {
    __syncthreads();
    if (t < 7) STAGE(t + 1, (t + 1) & 1);
    const int bsel = t & 1;
    const int kb = b * SLEN + kbase + t * 64;
    f32x4 s[4] = {};
#pragma unroll
    for (int e = 0; e < 4; ++e)
#pragma unroll
      for (int kf = 0; kf < 4; ++kf) {
        bf16x8 kv = *(const bf16x8*)&Klds[bsel][(e * 16 + lc) * 128 +
                                               (((kf * 4 + lg) ^ (lc & 7)) * 8)];
        s[e] = mfma16(kv, qf[kf], s[e]);
      }
    float wv[4][4];
#pragma unroll
    for (int e = 0; e < 4; ++e) {
      f32x4 k2v = *(const f32x4*)&k2a[kb + e * 16 + lg * 4];
#pragma unroll
      for (int r = 0; r < 4; ++r) {
        float d2 = q2s + k2v[r] - 2.0f * s[e][r];
        float g = __builtin_amdgcn_rcpf(fmaxf(d2, 1e-16f));
        wv[e][r] = g;
        den += g;
      }
    }
#pragma unroll
    for (int ksub = 0; ksub < 2; ++ksub) {
      bf16x8 pa;
#pragma unroll
      for (int r = 0; r < 4; ++r) {
        pa[r] = f2bf(wv[2 * ksub][r]);
        pa[4 + r] = f2bf(wv[2 * ksub + 1][r]);
      }
#pragma unroll
      for (int nv = 0; nv < 16; ++nv) {
        int dv = nv * 16 + lc;
        bf16x8 bv = *(const bf16x8*)&Vlds[bsel][dv * 64 +
                                               (((ksub * 4 + lg) ^ (dv & 7)) * 8)];
        acc[nv] = mfma16(pa, bv, acc[nv]);
      }
    }
  }
#undef STAGE
  den += __shfl_xor(den, 16, 64);
  den += __shfl_xor(den, 32, 64);
  const int qt32 = qt * 4 + (w >> 1);
  const int pb = ((b * 64 + qt32) << 2) | ks;
  if (l < 16) denp[pb * 32 + (w & 1) * 16 + lc] = den;
  const size_t pbase = (size_t)pb * 32 * 256;
#pragma unroll
  for (int nv = 0; nv < 16; ++nv) {
    int dv = nv * 16 + lc;
#pragma unroll
    for (int r = 0; r < 4; ++r) {
      int rit = (w & 1) * 16 + lg * 4 + r;
      nump[pbase + (size_t)rit * 256 + dv] = f2bf(acc[nv][r]);
    }
  }
}

// ---------------------------------------------------------------- gemm3 -----
// Fused k_red + GEMM: prologue builds AG tile (sum nump / sum denp * G) into
// swizzled LDS (64 KB); K-loop stages only B; epilogue adds X + bp.
// 1D grid 512: m0i = bid&63 so the 8 same-m0 blocks share an XCD (L2 reuse).
__global__ __launch_bounds__(256) void k_gemm3(
    const short* __restrict__ nump, const float* __restrict__ denp,
    const short* __restrict__ O, const short* __restrict__ WpT,
    const float* __restrict__ X, const float* __restrict__ bp,
    float* __restrict__ Y) {
  __shared__ short AGt[128 * 256];  // 64 KB, chunk-swizzled: byte ^= (r&31)<<4
  __shared__ short Bt[128 * 32];    //  8 KB
  const int tid = threadIdx.x;
  const int w = tid >> 6, l = tid & 63, lg = l >> 4, lc = l & 15;
  const int bid = blockIdx.x;
  const int m0 = (bid & 63) * 128, n0 = (bid >> 6) * 128;
  const int sr0 = w * 32 + (l >> 2);
  const int scc = (l & 3) * 8;
  const int wm = (w >> 1) * 64, wn = (w & 1) * 64;

  // ---- prologue: AG rows m0..m0+127 into AGt
  {
    int r = tid >> 1;                    // 0..127
    int row = m0 + r;
    int b_ = row >> 11, srow = row & 2047;
    int qt = srow >> 5, rit = srow & 31;
    int pbb = (b_ * 64 + qt) * 4;
    float den = 0.f;
#pragma unroll
    for (int ksi = 0; ksi < 4; ++ksi) den += denp[(pbb + ksi) * 32 + rit];
    float rden = 1.f / den;
    int dvh = (tid & 1) * 128;
#pragma unroll
    for (int ch = 0; ch < 16; ++ch) {
      int dv0 = dvh + ch * 8;
      float num[8] = {};
#pragma unroll
      for (int ksi = 0; ksi < 4; ++ksi) {
        bf16x8 v = *(const bf16x8*)&nump[((size_t)(pbb + ksi) * 32 + rit) * 256 + dv0];
#pragma unroll
        for (int j = 0; j < 8; ++j) num[j] += bf2f(v[j]);
      }
      bf16x8 gv = *(const bf16x8*)&O[(size_t)row * 768 + 512 + dv0];
      bf16x8 o;
#pragma unroll
      for (int j = 0; j < 8; ++j) o[j] = f2bf(num[j] * rden * bf2f(gv[j]));
      int byte = (r * 512 + dv0 * 2) ^ ((r & 31) << 4);
      *(bf16x8*)((char*)AGt + byte) = o;
    }
  }

  f32x4 acc[4][4] = {};
  const short* Bb = WpT + (size_t)n0 * 256;

  for (int kb = 0; kb < 256; kb += 32) {
    gld_lds16(Bb + (size_t)sr0 * 256 + kb + scc, &Bt[(w * 32) * 32]);
    gld_lds16(Bb + (size_t)(sr0 + 16) * 256 + kb + scc, &Bt[(w * 32 + 16) * 32]);
    __syncthreads();   // first pass also covers the AGt prologue writes
    bf16x8 af[4], bf[4];
#pragma unroll
    for (int mi = 0; mi < 4; ++mi) {
      int r = wm + mi * 16 + lc;
      int byte = (r * 512 + (kb + lg * 8) * 2) ^ ((r & 31) << 4);
      af[mi] = *(const bf16x8*)((const char*)AGt + byte);
    }
#pragma unroll
    for (int ni = 0; ni < 4; ++ni)
      bf[ni] = *(const bf16x8*)&Bt[(wn + ni * 16 + lc) * 32 + lg * 8];
#pragma unroll
    for (int mi = 0; mi < 4; ++mi)
#pragma unroll
      for (int ni = 0; ni < 4; ++ni)
        acc[mi][ni] = mfma16(af[mi], bf[ni], acc[mi][ni]);
    __syncthreads();
  }
#pragma unroll
  for (int mi = 0; mi < 4; ++mi) {
    int gr = m0 + wm + mi * 16 + lg * 4;
#pragma unroll
    for (int ni = 0; ni < 4; ++ni) {
      int gc = n0 + wn + ni * 16 + lc;
      float bias = bp[gc];
#pragma unroll
      for (int r = 0; r < 4; ++r) {
        size_t idx = (size_t)(gr + r) * 1024 + gc;
        Y[idx] = acc[mi][ni][r] + X[idx] + bias;
      }
    }
  }
}

// ---------------------------------------------------------------- launch ----
extern "C" void kernel_launch(void* const* d_in, const int* in_sizes, int n_in,
                              void* d_out, int out_size, void* d_ws, size_t ws_size,
                              hipStream_t stream) {
  const float* X  = (const float*)d_in[0];
  const float* Wq = (const float*)d_in[1];
  const float* bq = (const float*)d_in[2];
  const float* Wk = (const float*)d_in[3];
  const float* bk = (const float*)d_in[4];
  const float* Wv = (const float*)d_in[5];
  const float* bv = (const float*)d_in[6];
  const float* Wg = (const float*)d_in[7];
  const float* bg = (const float*)d_in[8];
  const float* Wp = (const float*)d_in[9];
  const float* bp = (const float*)d_in[10];

  char* ws = (char*)d_ws;
  short* WcatT = (short*)(ws + 0);          //  1,572,864 B
  short* WpT   = (short*)(ws + 1572864);    //    524,288 B
  float* bcat  = (float*)(ws + 2097152);    //      3,072 B (pad to 4096)
  short* O     = (short*)(ws + 2101248);    // 12,582,912 B  (QKVG bf16)
  short* Vtp   = (short*)(ws + 14684160);   //  4,194,304 B
  float* q2a   = (float*)(ws + 18878464);   //     32,768 B
  float* k2a   = (float*)(ws + 18911232);   //     32,768 B
  short* nump  = (short*)(ws + 18944000);   // 16,777,216 B
  float* denp  = (float*)(ws + 35721216);   //    131,072 B  (total ~35.9 MB)
  float* Y = (float*)d_out;

  hipLaunchKernelGGL(k_prep, dim3(257), dim3(256), 0, stream,
                     Wq, bq, Wk, bk, Wv, bv, Wg, bg, Wp, WcatT, WpT, bcat);
  hipLaunchKernelGGL(k_gemm1, dim3(64, 6), dim3(256), 0, stream, X, WcatT, bcat, O, q2a, k2a);
  hipLaunchKernelGGL(k_vt, dim3(1024), dim3(256), 0, stream, O, Vtp);
  hipLaunchKernelGGL(k_attn, dim3(256), dim3(512), 0, stream, O, Vtp, q2a, k2a, nump, denp);
  hipLaunchKernelGGL(k_gemm3, dim3(512), dim3(256), 0, stream, nump, denp, O, WpT, X, bp, Y);
}

// Round 10
// 194.868 us; speedup vs baseline: 1.1124x; 1.1124x over previous
//
#include <hip/hip_runtime.h>
#include <stdint.h>

// Problem sizes (fixed): B=4, S=2048, D=1024, DQK=128, DV=256
#define SLEN 2048
#define NROWS 8192   // B*S

typedef __attribute__((ext_vector_type(4))) float f32x4;
typedef __attribute__((ext_vector_type(8))) short bf16x8;
typedef __attribute__((ext_vector_type(2))) unsigned int u32x2;
typedef __attribute__((ext_vector_type(4))) unsigned int u32x4;

__device__ __forceinline__ short f2bf(float f) {
  uint32_t u = __builtin_bit_cast(uint32_t, f);
  u += 0x7FFFu + ((u >> 16) & 1u);
  return (short)(u >> 16);
}
__device__ __forceinline__ float bf2f(short s) {
  uint32_t u = ((uint32_t)(uint16_t)s) << 16;
  return __builtin_bit_cast(float, u);
}
__device__ __forceinline__ f32x4 mfma16(bf16x8 a, bf16x8 b, f32x4 c) {
  return __builtin_amdgcn_mfma_f32_16x16x32_bf16(a, b, c, 0, 0, 0);
}
__device__ __forceinline__ void gld_lds16(const void* g, void* l) {
  __builtin_amdgcn_global_load_lds(
      (const __attribute__((address_space(1))) void*)g,
      (__attribute__((address_space(3))) void*)l, 16, 0, 0);
}

// ---------------------------------------------------------------- prep ------
// blocks [0,256): LDS-tiled 64x64 weight transposes; block 256: bcat.
__global__ __launch_bounds__(256) void k_prep(
    const float* __restrict__ Wq, const float* __restrict__ bq,
    const float* __restrict__ Wk, const float* __restrict__ bk,
    const float* __restrict__ Wv, const float* __restrict__ bv,
    const float* __restrict__ Wg, const float* __restrict__ bg,
    const float* __restrict__ Wp,
    short* __restrict__ WcatT, short* __restrict__ WpT,
    float* __restrict__ bcat) {
  __shared__ short tl[64][72];
  int blk = blockIdx.x, tid = threadIdx.x;
  if (blk < 256) {
    int t = blk;
    const float* src; short* dst; int C, rowoff, dstC, r0, c0;
    if (t < 32)       { src = Wq; C = 128;  rowoff = 0;   dst = WcatT; dstC = 1024; r0 = (t >> 1) * 64;  c0 = (t & 1) * 64; }
    else if (t < 64)  { t -= 32;  src = Wk; C = 128;  rowoff = 128; dst = WcatT; dstC = 1024; r0 = (t >> 1) * 64;  c0 = (t & 1) * 64; }
    else if (t < 128) { t -= 64;  src = Wv; C = 256;  rowoff = 256; dst = WcatT; dstC = 1024; r0 = (t >> 2) * 64;  c0 = (t & 3) * 64; }
    else if (t < 192) { t -= 128; src = Wg; C = 256;  rowoff = 512; dst = WcatT; dstC = 1024; r0 = (t >> 2) * 64;  c0 = (t & 3) * 64; }
    else              { t -= 192; src = Wp; C = 1024; rowoff = 0;   dst = WpT;   dstC = 256;  r0 = (t >> 4) * 64;  c0 = (t & 15) * 64; }
    int lr = tid >> 4, lcc = tid & 15;
#pragma unroll
    for (int rr = 0; rr < 4; ++rr) {
      f32x4 v = *(const f32x4*)&src[(size_t)(r0 + lr * 4 + rr) * C + c0 + lcc * 4];
#pragma unroll
      for (int j = 0; j < 4; ++j) tl[lcc * 4 + j][lr * 4 + rr] = f2bf(v[j]);
    }
    __syncthreads();
    int orow = tid >> 2, og = (tid & 3) * 16;
    bf16x8 o1, o2;
#pragma unroll
    for (int j = 0; j < 8; ++j) { o1[j] = tl[orow][og + j]; o2[j] = tl[orow][og + 8 + j]; }
    size_t dbase = (size_t)(rowoff + c0 + orow) * dstC + r0 + og;
    *(bf16x8*)&dst[dbase] = o1;
    *(bf16x8*)&dst[dbase + 8] = o2;
  } else {
    int c = tid;
    if (c < 768) {
      float v;
      if (c < 128)      v = bq[c];
      else if (c < 256) v = bk[c - 128];
      else if (c < 512) v = bv[c - 256];
      else              v = bg[c - 512];
      bcat[c] = v;
    }
  }
}

// ---------------------------------------------------------------- gemm1 -----
// O[8192][768] = bf16(X)[8192][1024] @ Wcat + bcat. A staged as f32 directly
// from X (chunk-XOR pre-swizzled source, linear LDS dest), converted to bf16
// at frag-load time. Blocks y==0/1 also emit q2a/k2a row norms.
__global__ __launch_bounds__(256) void k_gemm1(
    const float* __restrict__ X, const short* __restrict__ WcatT,
    const float* __restrict__ bcat, short* __restrict__ O,
    float* __restrict__ q2a, float* __restrict__ k2a) {
  __shared__ float Atf[128 * 32];   // 16 KB, 16B-chunk swizzled per row
  __shared__ short Bt[128 * 32];    //  8 KB
  __shared__ float nlds[128][2];
  const int tid = threadIdx.x;
  const int w = tid >> 6, l = tid & 63, lg = l >> 4, lc = l & 15;
  const int m0 = blockIdx.x * 128, n0 = blockIdx.y * 128;
  const int sr0 = w * 32 + (l >> 2);
  const int scc = (l & 3) * 8;
  const int wm = (w >> 1) * 64, wn = (w & 1) * 64;
  const int arow = w * 8 + (l >> 3);
  const int achk = (l & 7) ^ (arow & 7);

  f32x4 acc[4][4] = {};
  const float* Ab = X + (size_t)m0 * 1024;
  const short* Bb = WcatT + (size_t)n0 * 1024;

  for (int kb = 0; kb < 1024; kb += 32) {
#pragma unroll
    for (int i = 0; i < 4; ++i)
      gld_lds16(Ab + (size_t)(i * 32 + arow) * 1024 + kb + achk * 4,
                &Atf[(i * 32 + w * 8) * 32 + l * 4]);
    gld_lds16(Bb + (size_t)sr0 * 1024 + kb + scc, &Bt[(w * 32) * 32]);
    gld_lds16(Bb + (size_t)(sr0 + 16) * 1024 + kb + scc, &Bt[(w * 32 + 16) * 32]);
    __syncthreads();
    bf16x8 af[4], bf[4];
#pragma unroll
    for (int mi = 0; mi < 4; ++mi) {
      int r = wm + mi * 16 + lc;
      f32x4 a0 = *(const f32x4*)&Atf[r * 32 + (((2 * lg) ^ (r & 7)) * 4)];
      f32x4 a1 = *(const f32x4*)&Atf[r * 32 + (((2 * lg + 1) ^ (r & 7)) * 4)];
#pragma unroll
      for (int j = 0; j < 4; ++j) {
        af[mi][j] = f2bf(a0[j]);
        af[mi][4 + j] = f2bf(a1[j]);
      }
    }
#pragma unroll
    for (int ni = 0; ni < 4; ++ni)
      bf[ni] = *(const bf16x8*)&Bt[(wn + ni * 16 + lc) * 32 + lg * 8];
#pragma unroll
    for (int mi = 0; mi < 4; ++mi)
#pragma unroll
      for (int ni = 0; ni < 4; ++ni)
        acc[mi][ni] = mfma16(af[mi], bf[ni], acc[mi][ni]);
    __syncthreads();
  }
  float sq[4][4] = {};
#pragma unroll
  for (int mi = 0; mi < 4; ++mi) {
    int gr = m0 + wm + mi * 16 + lg * 4;
#pragma unroll
    for (int ni = 0; ni < 4; ++ni) {
      int gc = n0 + wn + ni * 16 + lc;
      float bias = bcat[gc];
#pragma unroll
      for (int r = 0; r < 4; ++r) {
        short sv = f2bf(acc[mi][ni][r] + bias);
        O[(size_t)(gr + r) * 768 + gc] = sv;
        float v = bf2f(sv);
        sq[mi][r] += v * v;
      }
    }
  }
  if (blockIdx.y < 2) {
#pragma unroll
    for (int mi = 0; mi < 4; ++mi)
#pragma unroll
      for (int r = 0; r < 4; ++r) {
        float v = sq[mi][r];
        v += __shfl_xor(v, 1, 64); v += __shfl_xor(v, 2, 64);
        v += __shfl_xor(v, 4, 64); v += __shfl_xor(v, 8, 64);
        sq[mi][r] = v;
      }
    if (lc == 0) {
#pragma unroll
      for (int mi = 0; mi < 4; ++mi)
#pragma unroll
        for (int r = 0; r < 4; ++r)
          nlds[wm + mi * 16 + lg * 4 + r][w & 1] = sq[mi][r];
    }
    __syncthreads();
    if (tid < 128) {
      float t = nlds[tid][0] + nlds[tid][1];
      (blockIdx.y == 0 ? q2a : k2a)[m0 + tid] = t;
    }
  }
}

// ---------------------------------------------------------------- vt --------
// Vtp: V transposed AND k-permuted to match the in-register P fragment:
// pos(k) = (k>>5)*32 + ((k>>2)&3)*8 + ((k>>4)&1)*4 + (k&3)
__global__ __launch_bounds__(256) void k_vt(
    const short* __restrict__ O, short* __restrict__ Vtp) {
  __shared__ short tile[64][33];
  int blk = blockIdx.x, tid = threadIdx.x;
  int b = blk >> 8, rem = blk & 255;
  int s0 = (rem >> 3) * 64, dv0 = (rem & 7) * 32;
  int r = tid >> 2, cg = (tid & 3) * 8;
  bf16x8 v = *(const bf16x8*)&O[(size_t)(b * SLEN + s0 + r) * 768 + 256 + dv0 + cg];
#pragma unroll
  for (int j = 0; j < 8; ++j) tile[r][cg + j] = v[j];
  __syncthreads();
  int dr = tid >> 3, sg = (tid & 7) * 8;
  bf16x8 ov;
#pragma unroll
  for (int j = 0; j < 8; ++j) ov[j] = tile[sg + j][dr];
  int ka = s0 + sg;
  int c5 = ka >> 5, hi = (ka >> 4) & 1, lgq = (ka >> 2) & 3;
  size_t base = (size_t)(b * 256 + dv0 + dr) * SLEN + c5 * 32 + lgq * 8 + hi * 4;
  u32x4 od = __builtin_bit_cast(u32x4, ov);
  u32x2 p0; p0[0] = od[0]; p0[1] = od[1];
  u32x2 p1; p1[0] = od[2]; p1[1] = od[3];
  *(u32x2*)&Vtp[base] = p0;        // k = ka..ka+3
  *(u32x2*)&Vtp[base + 8] = p1;    // k = ka+4..ka+7
}

// ---------------------------------------------------------------- attn ------
// 8-wave flash structure (proven round 8): 512 thr, 128 q rows (16/wave),
// k-window 512 (ks split 4), 256 dv per wave. K/Vtp tiles double-buffered in
// LDS (96 KB), global_load_lds with pre-swizzled source + swizzled ds_read.
__global__ __launch_bounds__(512) void k_attn(
    const short* __restrict__ O, const short* __restrict__ Vtp,
    const float* __restrict__ q2a, const float* __restrict__ k2a,
    short* __restrict__ nump, float* __restrict__ denp) {
  __shared__ short Klds[2][64 * 128];
  __shared__ short Vlds[2][256 * 64];
  const int tid = threadIdx.x;
  const int w = tid >> 6, l = tid & 63, lg = l >> 4, lc = l & 15;
  const int gid = blockIdx.x;
  const int blk = ((gid & 7) << 5) | (gid >> 3);
  const int b = blk >> 6, qt = (blk >> 2) & 15, ks = blk & 3;
  const int grow0 = b * SLEN + qt * 128 + w * 16;
  const int kbase = ks * 512;

  bf16x8 qf[4];
#pragma unroll
  for (int kf = 0; kf < 4; ++kf)
    qf[kf] = *(const bf16x8*)&O[(size_t)(grow0 + lc) * 768 + kf * 32 + lg * 8];
  const float q2s = q2a[grow0 + lc];

  f32x4 acc[16] = {};
  float den = 0.f;

#define STAGE(T, BSEL)                                                        \
  {                                                                           \
    const int kt_ = kbase + (T) * 64;                                         \
    _Pragma("unroll")                                                         \
    for (int j = 0; j < 6; ++j) {                                             \
      int issue = w * 6 + j;                                                  \
      if (issue < 16) {                                                       \
        int kk = issue * 4 + (l >> 4);                                        \
        int c = l & 15;                                                       \
        const short* src = O + (size_t)(b * SLEN + kt_ + kk) * 768 + 128 +    \
                           ((c ^ (kk & 7)) * 8);                              \
        gld_lds16(src, &Klds[BSEL][issue * 512 + l * 8]);                     \
      } else {                                                                \
        int vj = issue - 16;                                                  \
        int dv = vj * 8 + (l >> 3);                                           \
        int c = l & 7;                                                        \
        const short* src = Vtp + (size_t)(b * 256 + dv) * SLEN + kt_ +        \
                           ((c ^ (dv & 7)) * 8);                              \
        gld_lds16(src, &Vlds[BSEL][vj * 512 + l * 8]);                        \
      }                                                                       \
    }                                                                         \
  }

  STAGE(0, 0);
  for (int t = 0; t < 8; ++t) {
    __syncthreads();
    if (t < 7) STAGE(t + 1, (t + 1) & 1);
    const int bsel = t & 1;
    const int kb = b * SLEN + kbase + t * 64;
    f32x4 s[4] = {};
#pragma unroll
    for (int e = 0; e < 4; ++e)
#pragma unroll
      for (int kf = 0; kf < 4; ++kf) {
        bf16x8 kv = *(const bf16x8*)&Klds[bsel][(e * 16 + lc) * 128 +
                                               (((kf * 4 + lg) ^ (lc & 7)) * 8)];
        s[e] = mfma16(kv, qf[kf], s[e]);
      }
    float wv[4][4];
#pragma unroll
    for (int e = 0; e < 4; ++e) {
      f32x4 k2v = *(const f32x4*)&k2a[kb + e * 16 + lg * 4];
#pragma unroll
      for (int r = 0; r < 4; ++r) {
        float d2 = q2s + k2v[r] - 2.0f * s[e][r];
        float g = __builtin_amdgcn_rcpf(fmaxf(d2, 1e-16f));
        wv[e][r] = g;
        den += g;
      }
    }
#pragma unroll
    for (int ksub = 0; ksub < 2; ++ksub) {
      bf16x8 pa;
#pragma unroll
      for (int r = 0; r < 4; ++r) {
        pa[r] = f2bf(wv[2 * ksub][r]);
        pa[4 + r] = f2bf(wv[2 * ksub + 1][r]);
      }
#pragma unroll
      for (int nv = 0; nv < 16; ++nv) {
        int dv = nv * 16 + lc;
        bf16x8 bv = *(const bf16x8*)&Vlds[bsel][dv * 64 +
                                               (((ksub * 4 + lg) ^ (dv & 7)) * 8)];
        acc[nv] = mfma16(pa, bv, acc[nv]);
      }
    }
  }
#undef STAGE
  den += __shfl_xor(den, 16, 64);
  den += __shfl_xor(den, 32, 64);
  const int qt32 = qt * 4 + (w >> 1);
  const int pb = ((b * 64 + qt32) << 2) | ks;
  if (l < 16) denp[pb * 32 + (w & 1) * 16 + lc] = den;
  const size_t pbase = (size_t)pb * 32 * 256;
#pragma unroll
  for (int nv = 0; nv < 16; ++nv) {
    int dv = nv * 16 + lc;
#pragma unroll
    for (int r = 0; r < 4; ++r) {
      int rit = (w & 1) * 16 + lg * 4 + r;
      nump[pbase + (size_t)rit * 256 + dv] = f2bf(acc[nv][r]);
    }
  }
}

// ---------------------------------------------------------------- red -------
// AG[row][dv] = (sum_ks nump) / (sum_ks denp) * G[row][dv]
__global__ __launch_bounds__(256) void k_red(
    const short* __restrict__ nump, const float* __restrict__ denp,
    const short* __restrict__ O, short* __restrict__ AG) {
  int flat = blockIdx.x * 256 + threadIdx.x;   // 0..262143
  int idx8 = flat * 8;
  int row = idx8 >> 8;
  int dv0 = idx8 & 255;
  int b = row >> 11, srow = row & 2047;
  int qt = srow >> 5, rit = srow & 31;
  int blkbase = (b * 64 + qt) << 2;
  float num[8] = {};
  float den = 0.f;
#pragma unroll
  for (int ksi = 0; ksi < 4; ++ksi) {
    const size_t base = ((size_t)(blkbase + ksi) * 32 + rit) * 256 + dv0;
    bf16x8 v = *(const bf16x8*)&nump[base];
#pragma unroll
    for (int j = 0; j < 8; ++j) num[j] += bf2f(v[j]);
    den += denp[(blkbase + ksi) * 32 + rit];
  }
  float rden = 1.f / den;
  bf16x8 gv = *(const bf16x8*)&O[(size_t)row * 768 + 512 + dv0];
  bf16x8 o;
#pragma unroll
  for (int j = 0; j < 8; ++j) o[j] = f2bf(num[j] * rden * bf2f(gv[j]));
  *(bf16x8*)&AG[idx8] = o;
}

// ---------------------------------------------------------------- gemm3 -----
// Y[8192][1024] = X + AG[8192][256] @ Wp + bp  (round-8 structure)
__global__ __launch_bounds__(256) void k_gemm3(
    const short* __restrict__ AG, const short* __restrict__ WpT,
    const float* __restrict__ X, const float* __restrict__ bp,
    float* __restrict__ Y) {
  __shared__ short At[128 * 32];
  __shared__ short Bt[128 * 32];
  const int tid = threadIdx.x;
  const int w = tid >> 6, l = tid & 63, lg = l >> 4, lc = l & 15;
  const int m0 = blockIdx.x * 128, n0 = blockIdx.y * 128;
  const int sr0 = w * 32 + (l >> 2);
  const int scc = (l & 3) * 8;
  const int wm = (w >> 1) * 64, wn = (w & 1) * 64;

  f32x4 acc[4][4] = {};
  const short* Ab = AG + (size_t)m0 * 256;
  const short* Bb = WpT + (size_t)n0 * 256;

  for (int kb = 0; kb < 256; kb += 32) {
    gld_lds16(Ab + (size_t)sr0 * 256 + kb + scc, &At[(w * 32) * 32]);
    gld_lds16(Ab + (size_t)(sr0 + 16) * 256 + kb + scc, &At[(w * 32 + 16) * 32]);
    gld_lds16(Bb + (size_t)sr0 * 256 + kb + scc, &Bt[(w * 32) * 32]);
    gld_lds16(Bb + (size_t)(sr0 + 16) * 256 + kb + scc, &Bt[(w * 32 + 16) * 32]);
    __syncthreads();
    bf16x8 af[4], bf[4];
#pragma unroll
    for (int mi = 0; mi < 4; ++mi)
      af[mi] = *(const bf16x8*)&At[(wm + mi * 16 + lc) * 32 + lg * 8];
#pragma unroll
    for (int ni = 0; ni < 4; ++ni)
      bf[ni] = *(const bf16x8*)&Bt[(wn + ni * 16 + lc) * 32 + lg * 8];
#pragma unroll
    for (int mi = 0; mi < 4; ++mi)
#pragma unroll
      for (int ni = 0; ni < 4; ++ni)
        acc[mi][ni] = mfma16(af[mi], bf[ni], acc[mi][ni]);
    __syncthreads();
  }
#pragma unroll
  for (int mi = 0; mi < 4; ++mi) {
    int gr = m0 + wm + mi * 16 + lg * 4;
#pragma unroll
    for (int ni = 0; ni < 4; ++ni) {
      int gc = n0 + wn + ni * 16 + lc;
      float bias = bp[gc];
#pragma unroll
      for (int r = 0; r < 4; ++r) {
        size_t idx = (size_t)(gr + r) * 1024 + gc;
        Y[idx] = acc[mi][ni][r] + X[idx] + bias;
      }
    }
  }
}

// ---------------------------------------------------------------- launch ----
extern "C" void kernel_launch(void* const* d_in, const int* in_sizes, int n_in,
                              void* d_out, int out_size, void* d_ws, size_t ws_size,
                              hipStream_t stream) {
  const float* X  = (const float*)d_in[0];
  const float* Wq = (const float*)d_in[1];
  const float* bq = (const float*)d_in[2];
  const float* Wk = (const float*)d_in[3];
  const float* bk = (const float*)d_in[4];
  const float* Wv = (const float*)d_in[5];
  const float* bv = (const float*)d_in[6];
  const float* Wg = (const float*)d_in[7];
  const float* bg = (const float*)d_in[8];
  const float* Wp = (const float*)d_in[9];
  const float* bp = (const float*)d_in[10];

  char* ws = (char*)d_ws;
  short* WcatT = (short*)(ws + 0);          //  1,572,864 B
  short* WpT   = (short*)(ws + 1572864);    //    524,288 B
  float* bcat  = (float*)(ws + 2097152);    //      4,096 B (pad)
  short* O     = (short*)(ws + 2101248);    // 12,582,912 B
  short* Vtp   = (short*)(ws + 14684160);   //  4,194,304 B
  float* q2a   = (float*)(ws + 18878464);   //     32,768 B
  float* k2a   = (float*)(ws + 18911232);   //     32,768 B
  short* nump  = (short*)(ws + 18944000);   // 16,777,216 B
  float* denp  = (float*)(ws + 35721216);   //    131,072 B
  short* AG    = (short*)(ws + 35852288);   //  4,194,304 B  (total ~40.0 MB)
  float* Y = (float*)d_out;

  hipLaunchKernelGGL(k_prep, dim3(257), dim3(256), 0, stream,
                     Wq, bq, Wk, bk, Wv, bv, Wg, bg, Wp, WcatT, WpT, bcat);
  hipLaunchKernelGGL(k_gemm1, dim3(64, 6), dim3(256), 0, stream, X, WcatT, bcat, O, q2a, k2a);
  hipLaunchKernelGGL(k_vt, dim3(1024), dim3(256), 0, stream, O, Vtp);
  hipLaunchKernelGGL(k_attn, dim3(256), dim3(512), 0, stream, O, Vtp, q2a, k2a, nump, denp);
  hipLaunchKernelGGL(k_red, dim3(1024), dim3(256), 0, stream, nump, denp, O, AG);
  hipLaunchKernelGGL(k_gemm3, dim3(64, 8), dim3(256), 0, stream, AG, WpT, X, bp, Y);
}

// Round 11
// 186.683 us; speedup vs baseline: 1.1612x; 1.0438x over previous
//
#include <hip/hip_runtime.h>
#include <stdint.h>

// Problem sizes (fixed): B=4, S=2048, D=1024, DQK=128, DV=256
#define SLEN 2048
#define NROWS 8192   // B*S

typedef __attribute__((ext_vector_type(4))) float f32x4;
typedef __attribute__((ext_vector_type(8))) short bf16x8;
typedef __attribute__((ext_vector_type(2))) unsigned int u32x2;
typedef __attribute__((ext_vector_type(4))) unsigned int u32x4;

__device__ __forceinline__ short f2bf(float f) {
  uint32_t u = __builtin_bit_cast(uint32_t, f);
  u += 0x7FFFu + ((u >> 16) & 1u);
  return (short)(u >> 16);
}
__device__ __forceinline__ float bf2f(short s) {
  uint32_t u = ((uint32_t)(uint16_t)s) << 16;
  return __builtin_bit_cast(float, u);
}
__device__ __forceinline__ f32x4 mfma16(bf16x8 a, bf16x8 b, f32x4 c) {
  return __builtin_amdgcn_mfma_f32_16x16x32_bf16(a, b, c, 0, 0, 0);
}
__device__ __forceinline__ void gld_lds16(const void* g, void* l) {
  __builtin_amdgcn_global_load_lds(
      (const __attribute__((address_space(1))) void*)g,
      (__attribute__((address_space(3))) void*)l, 16, 0, 0);
}

// ---------------------------------------------------------------- prep ------
// Round-8 version: X->Xb bf16 cast (blocks [0,4096)), weight transposes
// [4096,4352), bcat 4352. The cast pays for itself: gemm1 stages half the
// bytes vs f32-direct (round-10 regression: +25 us in gemm1 for -9 in prep).
__global__ __launch_bounds__(256) void k_prep(
    const float* __restrict__ X,
    const float* __restrict__ Wq, const float* __restrict__ bq,
    const float* __restrict__ Wk, const float* __restrict__ bk,
    const float* __restrict__ Wv, const float* __restrict__ bv,
    const float* __restrict__ Wg, const float* __restrict__ bg,
    const float* __restrict__ Wp,
    short* __restrict__ Xb, short* __restrict__ WcatT,
    short* __restrict__ WpT, float* __restrict__ bcat) {
  __shared__ short tl[64][72];
  int blk = blockIdx.x, tid = threadIdx.x;
  if (blk < 4096) {
    size_t e = ((size_t)blk * 256 + tid) * 8;
    f32x4 a = *(const f32x4*)&X[e];
    f32x4 b = *(const f32x4*)&X[e + 4];
    bf16x8 o;
    o[0] = f2bf(a[0]); o[1] = f2bf(a[1]); o[2] = f2bf(a[2]); o[3] = f2bf(a[3]);
    o[4] = f2bf(b[0]); o[5] = f2bf(b[1]); o[6] = f2bf(b[2]); o[7] = f2bf(b[3]);
    *(bf16x8*)&Xb[e] = o;
  } else if (blk < 4352) {
    int t = blk - 4096;
    const float* src; short* dst; int C, rowoff, dstC, r0, c0;
    if (t < 32)       { src = Wq; C = 128;  rowoff = 0;   dst = WcatT; dstC = 1024; r0 = (t >> 1) * 64;  c0 = (t & 1) * 64; }
    else if (t < 64)  { t -= 32;  src = Wk; C = 128;  rowoff = 128; dst = WcatT; dstC = 1024; r0 = (t >> 1) * 64;  c0 = (t & 1) * 64; }
    else if (t < 128) { t -= 64;  src = Wv; C = 256;  rowoff = 256; dst = WcatT; dstC = 1024; r0 = (t >> 2) * 64;  c0 = (t & 3) * 64; }
    else if (t < 192) { t -= 128; src = Wg; C = 256;  rowoff = 512; dst = WcatT; dstC = 1024; r0 = (t >> 2) * 64;  c0 = (t & 3) * 64; }
    else              { t -= 192; src = Wp; C = 1024; rowoff = 0;   dst = WpT;   dstC = 256;  r0 = (t >> 4) * 64;  c0 = (t & 15) * 64; }
    int lr = tid >> 4, lcc = tid & 15;
#pragma unroll
    for (int rr = 0; rr < 4; ++rr) {
      f32x4 v = *(const f32x4*)&src[(size_t)(r0 + lr * 4 + rr) * C + c0 + lcc * 4];
#pragma unroll
      for (int j = 0; j < 4; ++j) tl[lcc * 4 + j][lr * 4 + rr] = f2bf(v[j]);
    }
    __syncthreads();
    int orow = tid >> 2, og = (tid & 3) * 16;
    bf16x8 o1, o2;
#pragma unroll
    for (int j = 0; j < 8; ++j) { o1[j] = tl[orow][og + j]; o2[j] = tl[orow][og + 8 + j]; }
    size_t dbase = (size_t)(rowoff + c0 + orow) * dstC + r0 + og;
    *(bf16x8*)&dst[dbase] = o1;
    *(bf16x8*)&dst[dbase + 8] = o2;
  } else {
    int c = tid;
    if (c < 768) {
      float v;
      if (c < 128)      v = bq[c];
      else if (c < 256) v = bk[c - 128];
      else if (c < 512) v = bv[c - 256];
      else              v = bg[c - 512];
      bcat[c] = v;
    }
  }
}

// ---------------------------------------------------------------- gemm1 -----
// Round-8 version: O = Xb @ Wcat + bcat, bf16 LDS staging both operands.
// Blocks y==0/1 also emit q2a/k2a row norms.
__global__ __launch_bounds__(256) void k_gemm1(
    const short* __restrict__ Xb, const short* __restrict__ WcatT,
    const float* __restrict__ bcat, short* __restrict__ O,
    float* __restrict__ q2a, float* __restrict__ k2a) {
  __shared__ short At[128 * 32];
  __shared__ short Bt[128 * 32];
  __shared__ float nlds[128][2];
  const int tid = threadIdx.x;
  const int w = tid >> 6, l = tid & 63, lg = l >> 4, lc = l & 15;
  const int m0 = blockIdx.x * 128, n0 = blockIdx.y * 128;
  const int sr0 = w * 32 + (l >> 2);
  const int scc = (l & 3) * 8;
  const int wm = (w >> 1) * 64, wn = (w & 1) * 64;

  f32x4 acc[4][4] = {};
  const short* Ab = Xb + (size_t)m0 * 1024;
  const short* Bb = WcatT + (size_t)n0 * 1024;

  for (int kb = 0; kb < 1024; kb += 32) {
    gld_lds16(Ab + (size_t)sr0 * 1024 + kb + scc, &At[(w * 32) * 32]);
    gld_lds16(Ab + (size_t)(sr0 + 16) * 1024 + kb + scc, &At[(w * 32 + 16) * 32]);
    gld_lds16(Bb + (size_t)sr0 * 1024 + kb + scc, &Bt[(w * 32) * 32]);
    gld_lds16(Bb + (size_t)(sr0 + 16) * 1024 + kb + scc, &Bt[(w * 32 + 16) * 32]);
    __syncthreads();
    bf16x8 af[4], bf[4];
#pragma unroll
    for (int mi = 0; mi < 4; ++mi)
      af[mi] = *(const bf16x8*)&At[(wm + mi * 16 + lc) * 32 + lg * 8];
#pragma unroll
    for (int ni = 0; ni < 4; ++ni)
      bf[ni] = *(const bf16x8*)&Bt[(wn + ni * 16 + lc) * 32 + lg * 8];
#pragma unroll
    for (int mi = 0; mi < 4; ++mi)
#pragma unroll
      for (int ni = 0; ni < 4; ++ni)
        acc[mi][ni] = mfma16(af[mi], bf[ni], acc[mi][ni]);
    __syncthreads();
  }
  float sq[4][4] = {};
#pragma unroll
  for (int mi = 0; mi < 4; ++mi) {
    int gr = m0 + wm + mi * 16 + lg * 4;
#pragma unroll
    for (int ni = 0; ni < 4; ++ni) {
      int gc = n0 + wn + ni * 16 + lc;
      float bias = bcat[gc];
#pragma unroll
      for (int r = 0; r < 4; ++r) {
        short sv = f2bf(acc[mi][ni][r] + bias);
        O[(size_t)(gr + r) * 768 + gc] = sv;
        float v = bf2f(sv);
        sq[mi][r] += v * v;
      }
    }
  }
  if (blockIdx.y < 2) {
#pragma unroll
    for (int mi = 0; mi < 4; ++mi)
#pragma unroll
      for (int r = 0; r < 4; ++r) {
        float v = sq[mi][r];
        v += __shfl_xor(v, 1, 64); v += __shfl_xor(v, 2, 64);
        v += __shfl_xor(v, 4, 64); v += __shfl_xor(v, 8, 64);
        sq[mi][r] = v;
      }
    if (lc == 0) {
#pragma unroll
      for (int mi = 0; mi < 4; ++mi)
#pragma unroll
        for (int r = 0; r < 4; ++r)
          nlds[wm + mi * 16 + lg * 4 + r][w & 1] = sq[mi][r];
    }
    __syncthreads();
    if (tid < 128) {
      float t = nlds[tid][0] + nlds[tid][1];
      (blockIdx.y == 0 ? q2a : k2a)[m0 + tid] = t;
    }
  }
}

// ---------------------------------------------------------------- vt --------
// Vtp: V transposed AND k-permuted to match the in-register P fragment:
// pos(k) = (k>>5)*32 + ((k>>2)&3)*8 + ((k>>4)&1)*4 + (k&3)
__global__ __launch_bounds__(256) void k_vt(
    const short* __restrict__ O, short* __restrict__ Vtp) {
  __shared__ short tile[64][33];
  int blk = blockIdx.x, tid = threadIdx.x;
  int b = blk >> 8, rem = blk & 255;
  int s0 = (rem >> 3) * 64, dv0 = (rem & 7) * 32;
  int r = tid >> 2, cg = (tid & 3) * 8;
  bf16x8 v = *(const bf16x8*)&O[(size_t)(b * SLEN + s0 + r) * 768 + 256 + dv0 + cg];
#pragma unroll
  for (int j = 0; j < 8; ++j) tile[r][cg + j] = v[j];
  __syncthreads();
  int dr = tid >> 3, sg = (tid & 7) * 8;
  bf16x8 ov;
#pragma unroll
  for (int j = 0; j < 8; ++j) ov[j] = tile[sg + j][dr];
  int ka = s0 + sg;
  int c5 = ka >> 5, hi = (ka >> 4) & 1, lgq = (ka >> 2) & 3;
  size_t base = (size_t)(b * 256 + dv0 + dr) * SLEN + c5 * 32 + lgq * 8 + hi * 4;
  u32x4 od = __builtin_bit_cast(u32x4, ov);
  u32x2 p0; p0[0] = od[0]; p0[1] = od[1];
  u32x2 p1; p1[0] = od[2]; p1[1] = od[3];
  *(u32x2*)&Vtp[base] = p0;        // k = ka..ka+3
  *(u32x2*)&Vtp[base + 8] = p1;    // k = ka+4..ka+7
}

// ---------------------------------------------------------------- attn ------
// 8-wave flash structure, occupancy-doubled vs round 8: KT=32 (LDS 48 KB) and
// ks split 8 (grid 512) -> 2 blocks/CU = 4 waves/SIMD. Same swizzles (V XOR
// width 4), same in-register P->PV path, one barrier per tile.
__global__ __launch_bounds__(512) void k_attn(
    const short* __restrict__ O, const short* __restrict__ Vtp,
    const float* __restrict__ q2a, const float* __restrict__ k2a,
    short* __restrict__ nump, float* __restrict__ denp) {
  __shared__ short Klds[2][32 * 128];   //  8 KB each
  __shared__ short Vlds[2][256 * 32];   // 16 KB each  (total 48 KB)
  const int tid = threadIdx.x;
  const int w = tid >> 6, l = tid & 63, lg = l >> 4, lc = l & 15;
  const int gid = blockIdx.x;
  const int blk = ((gid & 7) << 6) | (gid >> 3);   // XCD swizzle (512%8==0)
  const int b = blk >> 7, qt = (blk >> 3) & 15, ks = blk & 7;
  const int grow0 = b * SLEN + qt * 128 + w * 16;
  const int kbase = ks * 256;

  bf16x8 qf[4];
#pragma unroll
  for (int kf = 0; kf < 4; ++kf)
    qf[kf] = *(const bf16x8*)&O[(size_t)(grow0 + lc) * 768 + kf * 32 + lg * 8];
  const float q2s = q2a[grow0 + lc];

  f32x4 acc[16] = {};
  float den = 0.f;

#define STAGE(T, BSEL)                                                        \
  {                                                                           \
    const int kt_ = kbase + (T) * 32;                                         \
    _Pragma("unroll")                                                         \
    for (int j = 0; j < 3; ++j) {                                             \
      int issue = w * 3 + j;                                                  \
      if (issue < 8) {                                                        \
        int kk = issue * 4 + (l >> 4);                                        \
        int c = l & 15;                                                       \
        const short* src = O + (size_t)(b * SLEN + kt_ + kk) * 768 + 128 +    \
                           ((c ^ (kk & 7)) * 8);                              \
        gld_lds16(src, &Klds[BSEL][issue * 512 + l * 8]);                     \
      } else {                                                                \
        int vj = issue - 8;                                                   \
        int dv = vj * 16 + (l >> 2);                                          \
        int c = l & 3;                                                        \
        const short* src = Vtp + (size_t)(b * 256 + dv) * SLEN + kt_ +        \
                           ((c ^ (dv & 3)) * 8);                              \
        gld_lds16(src, &Vlds[BSEL][vj * 512 + l * 8]);                        \
      }                                                                       \
    }                                                                         \
  }

  STAGE(0, 0);
  for (int t = 0; t < 8; ++t) {
    __syncthreads();               // drains stage(t); prev compute done
    if (t < 7) STAGE(t + 1, (t + 1) & 1);
    const int bsel = t & 1;
    const int kb = b * SLEN + kbase + t * 32;
    // QK^T (swapped: A=K from LDS, B=Q regs) -> s[e]: q=lc, k=e*16+lg*4+r
    f32x4 s[2] = {};
#pragma unroll
    for (int e = 0; e < 2; ++e)
#pragma unroll
      for (int kf = 0; kf < 4; ++kf) {
        bf16x8 kv = *(const bf16x8*)&Klds[bsel][(e * 16 + lc) * 128 +
                                               (((kf * 4 + lg) ^ (lc & 7)) * 8)];
        s[e] = mfma16(kv, qf[kf], s[e]);
      }
    float wv[2][4];
#pragma unroll
    for (int e = 0; e < 2; ++e) {
      f32x4 k2v = *(const f32x4*)&k2a[kb + e * 16 + lg * 4];
#pragma unroll
      for (int r = 0; r < 4; ++r) {
        float d2 = q2s + k2v[r] - 2.0f * s[e][r];
        float g = __builtin_amdgcn_rcpf(fmaxf(d2, 1e-16f));
        wv[e][r] = g;
        den += g;
      }
    }
    bf16x8 pa;
#pragma unroll
    for (int r = 0; r < 4; ++r) {
      pa[r] = f2bf(wv[0][r]);      // slots 0-3: k = lg*4+r
      pa[4 + r] = f2bf(wv[1][r]);  // slots 4-7: k = 16+lg*4+r
    }
#pragma unroll
    for (int nv = 0; nv < 16; ++nv) {
      int dv = nv * 16 + lc;
      bf16x8 bv = *(const bf16x8*)&Vlds[bsel][dv * 32 + ((lg ^ (dv & 3)) * 8)];
      acc[nv] = mfma16(pa, bv, acc[nv]);
    }
  }
#undef STAGE
  den += __shfl_xor(den, 16, 64);
  den += __shfl_xor(den, 32, 64);
  const int qt32 = qt * 4 + (w >> 1);
  const int pb = ((b * 64 + qt32) << 3) | ks;
  if (l < 16) denp[pb * 32 + (w & 1) * 16 + lc] = den;
  const size_t pbase = (size_t)pb * 32 * 256;
#pragma unroll
  for (int nv = 0; nv < 16; ++nv) {
    int dv = nv * 16 + lc;
#pragma unroll
    for (int r = 0; r < 4; ++r) {
      int rit = (w & 1) * 16 + lg * 4 + r;
      nump[pbase + (size_t)rit * 256 + dv] = f2bf(acc[nv][r]);
    }
  }
}

// ---------------------------------------------------------------- red -------
// AG[row][dv] = (sum over 8 ks of nump) / (sum denp) * G[row][dv]
__global__ __launch_bounds__(256) void k_red(
    const short* __restrict__ nump, const float* __restrict__ denp,
    const short* __restrict__ O, short* __restrict__ AG) {
  int flat = blockIdx.x * 256 + threadIdx.x;   // 0..262143
  int idx8 = flat * 8;
  int row = idx8 >> 8;
  int dv0 = idx8 & 255;
  int b = row >> 11, srow = row & 2047;
  int qt = srow >> 5, rit = srow & 31;
  int blkbase = (b * 64 + qt) << 3;
  float num[8] = {};
  float den = 0.f;
#pragma unroll
  for (int ksi = 0; ksi < 8; ++ksi) {
    const size_t base = ((size_t)(blkbase + ksi) * 32 + rit) * 256 + dv0;
    bf16x8 v = *(const bf16x8*)&nump[base];
#pragma unroll
    for (int j = 0; j < 8; ++j) num[j] += bf2f(v[j]);
    den += denp[(blkbase + ksi) * 32 + rit];
  }
  float rden = 1.f / den;
  bf16x8 gv = *(const bf16x8*)&O[(size_t)row * 768 + 512 + dv0];
  bf16x8 o;
#pragma unroll
  for (int j = 0; j < 8; ++j) o[j] = f2bf(num[j] * rden * bf2f(gv[j]));
  *(bf16x8*)&AG[idx8] = o;
}

// ---------------------------------------------------------------- gemm3 -----
// Y[8192][1024] = X + AG[8192][256] @ Wp + bp  (round-8 structure)
__global__ __launch_bounds__(256) void k_gemm3(
    const short* __restrict__ AG, const short* __restrict__ WpT,
    const float* __restrict__ X, const float* __restrict__ bp,
    float* __restrict__ Y) {
  __shared__ short At[128 * 32];
  __shared__ short Bt[128 * 32];
  const int tid = threadIdx.x;
  const int w = tid >> 6, l = tid & 63, lg = l >> 4, lc = l & 15;
  const int m0 = blockIdx.x * 128, n0 = blockIdx.y * 128;
  const int sr0 = w * 32 + (l >> 2);
  const int scc = (l & 3) * 8;
  const int wm = (w >> 1) * 64, wn = (w & 1) * 64;

  f32x4 acc[4][4] = {};
  const short* Ab = AG + (size_t)m0 * 256;
  const short* Bb = WpT + (size_t)n0 * 256;

  for (int kb = 0; kb < 256; kb += 32) {
    gld_lds16(Ab + (size_t)sr0 * 256 + kb + scc, &At[(w * 32) * 32]);
    gld_lds16(Ab + (size_t)(sr0 + 16) * 256 + kb + scc, &At[(w * 32 + 16) * 32]);
    gld_lds16(Bb + (size_t)sr0 * 256 + kb + scc, &Bt[(w * 32) * 32]);
    gld_lds16(Bb + (size_t)(sr0 + 16) * 256 + kb + scc, &Bt[(w * 32 + 16) * 32]);
    __syncthreads();
    bf16x8 af[4], bf[4];
#pragma unroll
    for (int mi = 0; mi < 4; ++mi)
      af[mi] = *(const bf16x8*)&At[(wm + mi * 16 + lc) * 32 + lg * 8];
#pragma unroll
    for (int ni = 0; ni < 4; ++ni)
      bf[ni] = *(const bf16x8*)&Bt[(wn + ni * 16 + lc) * 32 + lg * 8];
#pragma unroll
    for (int mi = 0; mi < 4; ++mi)
#pragma unroll
      for (int ni = 0; ni < 4; ++ni)
        acc[mi][ni] = mfma16(af[mi], bf[ni], acc[mi][ni]);
    __syncthreads();
  }
#pragma unroll
  for (int mi = 0; mi < 4; ++mi) {
    int gr = m0 + wm + mi * 16 + lg * 4;
#pragma unroll
    for (int ni = 0; ni < 4; ++ni) {
      int gc = n0 + wn + ni * 16 + lc;
      float bias = bp[gc];
#pragma unroll
      for (int r = 0; r < 4; ++r) {
        size_t idx = (size_t)(gr + r) * 1024 + gc;
        Y[idx] = acc[mi][ni][r] + X[idx] + bias;
      }
    }
  }
}

// ---------------------------------------------------------------- launch ----
extern "C" void kernel_launch(void* const* d_in, const int* in_sizes, int n_in,
                              void* d_out, int out_size, void* d_ws, size_t ws_size,
                              hipStream_t stream) {
  const float* X  = (const float*)d_in[0];
  const float* Wq = (const float*)d_in[1];
  const float* bq = (const float*)d_in[2];
  const float* Wk = (const float*)d_in[3];
  const float* bk = (const float*)d_in[4];
  const float* Wv = (const float*)d_in[5];
  const float* bv = (const float*)d_in[6];
  const float* Wg = (const float*)d_in[7];
  const float* bg = (const float*)d_in[8];
  const float* Wp = (const float*)d_in[9];
  const float* bp = (const float*)d_in[10];

  char* ws = (char*)d_ws;
  short* Xb    = (short*)(ws + 0);          // 16,777,216 B
  short* WcatT = (short*)(ws + 16777216);   //  1,572,864 B
  short* WpT   = (short*)(ws + 18350080);   //    524,288 B
  float* bcat  = (float*)(ws + 18874368);   //      4,096 B
  short* O     = (short*)(ws + 18878464);   // 12,582,912 B
  short* Vtp   = (short*)(ws + 31461376);   //  4,194,304 B
  float* q2a   = (float*)(ws + 35655680);   //     32,768 B
  float* k2a   = (float*)(ws + 35688448);   //     32,768 B
  short* nump  = (short*)(ws + 35721216);   // 33,554,432 B (8 ks partials)
  float* denp  = (float*)(ws + 69275648);   //    262,144 B
  short* AG    = (short*)(ws + 69537792);   //  4,194,304 B  (total ~70.3 MB)
  float* Y = (float*)d_out;

  hipLaunchKernelGGL(k_prep, dim3(4353), dim3(256), 0, stream,
                     X, Wq, bq, Wk, bk, Wv, bv, Wg, bg, Wp, Xb, WcatT, WpT, bcat);
  hipLaunchKernelGGL(k_gemm1, dim3(64, 6), dim3(256), 0, stream, Xb, WcatT, bcat, O, q2a, k2a);
  hipLaunchKernelGGL(k_vt, dim3(1024), dim3(256), 0, stream, O, Vtp);
  hipLaunchKernelGGL(k_attn, dim3(512), dim3(512), 0, stream, O, Vtp, q2a, k2a, nump, denp);
  hipLaunchKernelGGL(k_red, dim3(1024), dim3(256), 0, stream, nump, denp, O, AG);
  hipLaunchKernelGGL(k_gemm3, dim3(64, 8), dim3(256), 0, stream, AG, WpT, X, bp, Y);
}